// Round 8
// baseline (603.482 us; speedup 1.0000x reference)
//
#include <hip/hip_runtime.h>

#define H 128
#define EPS 1e-12f

typedef unsigned int u32x4 __attribute__((ext_vector_type(4)));

static __device__ __forceinline__ float bf_lo(unsigned int v) {
    return __uint_as_float(v << 16);
}
static __device__ __forceinline__ float bf_hi(unsigned int v) {
    return __uint_as_float(v & 0xFFFF0000u);
}
static __device__ __forceinline__ unsigned int f2bf_rne(float f) {
    unsigned int u = __float_as_uint(f);
    return (u + 0x7FFFu + ((u >> 16) & 1u)) >> 16;
}

// sum over 8 bf16 pairs with diag d folded in
static __device__ __forceinline__ float dot8(uint4 a, uint4 b,
                                             float4 d0, float4 d1, float p) {
    p = fmaf(bf_lo(a.x) * d0.x, bf_lo(b.x), p);
    p = fmaf(bf_hi(a.x) * d0.y, bf_hi(b.x), p);
    p = fmaf(bf_lo(a.y) * d0.z, bf_lo(b.y), p);
    p = fmaf(bf_hi(a.y) * d0.w, bf_hi(b.y), p);
    p = fmaf(bf_lo(a.z) * d1.x, bf_lo(b.z), p);
    p = fmaf(bf_hi(a.z) * d1.y, bf_hi(b.z), p);
    p = fmaf(bf_lo(a.w) * d1.z, bf_lo(b.w), p);
    p = fmaf(bf_hi(a.w) * d1.w, bf_hi(b.w), p);
    return p;
}

// Normalize rows, quantize to bf16, 256B/row pool (row-major).
__global__ void norm_quant_kernel(const float* __restrict__ emb,
                                  unsigned int* __restrict__ pool,
                                  int n_nodes) {
    int row = blockIdx.x * (blockDim.x >> 6) + (threadIdx.x >> 6);
    if (row >= n_nodes) return;
    int lane = threadIdx.x & 63;
    const float* p = emb + (size_t)row * H + lane * 2;
    float vx = __builtin_nontemporal_load(p);
    float vy = __builtin_nontemporal_load(p + 1);
    float ss = vx * vx + vy * vy;
#pragma unroll
    for (int off = 32; off; off >>= 1) ss += __shfl_xor(ss, off);
    float inv = 1.0f / fmaxf(sqrtf(ss), EPS);
    pool[(size_t)row * 64 + lane] =
        f2bf_rne(vx * inv) | (f2bf_rne(vy * inv) << 16);
}

// ---- bucket sort by src>>6 (64-node buckets): hist -> scan -> scatter ----

__global__ void hist_kernel(const int* __restrict__ src,
                            unsigned int* __restrict__ cnt,
                            int n_edges) {
    int tid = blockIdx.x * blockDim.x + threadIdx.x;
    int stride = gridDim.x * blockDim.x;
    for (int e = tid; e < n_edges; e += stride) {
        int s = __builtin_nontemporal_load(src + e);
        atomicAdd(&cnt[((unsigned)s) >> 6], 1u);
    }
}

// single-block exclusive scan in place (nb <= ~4096)
__global__ void scan_kernel(unsigned int* __restrict__ cur, int nb) {
    __shared__ unsigned int part[256];
    int t = threadIdx.x;
    int chunk = (nb + 255) / 256;
    int lo = t * chunk;
    int hi = lo + chunk < nb ? lo + chunk : nb;
    unsigned int sum = 0;
    for (int i = lo; i < hi; ++i) sum += cur[i];
    part[t] = sum;
    __syncthreads();
    if (t == 0) {
        unsigned int acc = 0;
        for (int i = 0; i < 256; ++i) {
            unsigned int v = part[i];
            part[i] = acc;
            acc += v;
        }
    }
    __syncthreads();
    unsigned int acc = part[t];
    for (int i = lo; i < hi; ++i) {
        unsigned int v = cur[i];
        cur[i] = acc;
        acc += v;
    }
}

__global__ void scatter_kernel(const int* __restrict__ src,
                               const int* __restrict__ dst,
                               unsigned int* __restrict__ cur,
                               u32x4* __restrict__ sorted,
                               int n_edges) {
    int tid = blockIdx.x * blockDim.x + threadIdx.x;
    int stride = gridDim.x * blockDim.x;
    for (int e = tid; e < n_edges; e += stride) {
        int s = __builtin_nontemporal_load(src + e);
        int t = __builtin_nontemporal_load(dst + e);
        unsigned int pos = atomicAdd(&cur[((unsigned)s) >> 6], 1u);
        u32x4 rec = {(unsigned)s, (unsigned)t, (unsigned)e, 0u};
        sorted[pos] = rec;  // bucket-sequential; let L2 merge
    }
}

// Edge pass over src-sorted edges: 8 lanes/edge, 2 batches per wave-iter.
// Src rows are bucket-local (16KB window) -> L1/L2 hits; dst random.
__global__ void edge_dot_sorted_kernel(const uint4* __restrict__ pool,
                                       const u32x4* __restrict__ sorted,
                                       const float* __restrict__ d,
                                       const float* __restrict__ scale,
                                       float* __restrict__ out,
                                       int n_edges) {
    int lane = threadIdx.x & 63;
    int sub  = lane >> 3;
    int q    = lane & 7;

    float4 dv0 = ((const float4*)d)[q * 4 + 0];
    float4 dv1 = ((const float4*)d)[q * 4 + 1];
    float4 dv2 = ((const float4*)d)[q * 4 + 2];
    float4 dv3 = ((const float4*)d)[q * 4 + 3];
    float sc = scale[0];

    int waveId = (blockIdx.x * blockDim.x + threadIdx.x) >> 6;
    int nWaves = (gridDim.x * blockDim.x) >> 6;
    int last = n_edges - 1;

    for (int ebase = waveId * 16; ebase < n_edges; ebase += nWaves * 16) {
        int e0 = ebase + sub;
        int e1 = ebase + 8 + sub;
        bool w0 = (e0 < n_edges);
        bool w1 = (e1 < n_edges);
        int c0 = w0 ? e0 : last;
        int c1 = w1 ? e1 : last;

        u32x4 r0 = __builtin_nontemporal_load(sorted + c0);
        u32x4 r1 = __builtin_nontemporal_load(sorted + c1);

        const uint4* pa0 = pool + (size_t)r0.x * 16 + q * 2;
        const uint4* pb0 = pool + (size_t)r0.y * 16 + q * 2;
        const uint4* pa1 = pool + (size_t)r1.x * 16 + q * 2;
        const uint4* pb1 = pool + (size_t)r1.y * 16 + q * 2;
        uint4 a00 = pa0[0];
        uint4 a01 = pa0[1];
        uint4 b00 = pb0[0];
        uint4 b01 = pb0[1];
        uint4 a10 = pa1[0];
        uint4 a11 = pa1[1];
        uint4 b10 = pb1[0];
        uint4 b11 = pb1[1];

        float p0 = dot8(a00, b00, dv0, dv1, 0.0f);
        p0 = dot8(a01, b01, dv2, dv3, p0);
        float p1 = dot8(a10, b10, dv0, dv1, 0.0f);
        p1 = dot8(a11, b11, dv2, dv3, p1);

        p0 += __shfl_xor(p0, 1);
        p1 += __shfl_xor(p1, 1);
        p0 += __shfl_xor(p0, 2);
        p1 += __shfl_xor(p1, 2);
        p0 += __shfl_xor(p0, 4);
        p1 += __shfl_xor(p1, 4);

        if (q == 0) {
            // scattered 4B stores: plain (cached) so L2 merges lines
            if (w0) out[r0.z] = p0 * sc;
            if (w1) out[r1.z] = p1 * sc;
        }
    }
}

// ---------------- R4 path (proven 124 us total) ----------------

__global__ void edge_dot_bf16_kernel(const uint4* __restrict__ pool,
                                     const int* __restrict__ src,
                                     const int* __restrict__ dst,
                                     const float* __restrict__ d,
                                     const float* __restrict__ scale,
                                     float* __restrict__ out,
                                     int n_edges) {
    int lane = threadIdx.x & 63;
    int sub  = lane >> 3;
    int q    = lane & 7;

    float4 dv0 = ((const float4*)d)[q * 4 + 0];
    float4 dv1 = ((const float4*)d)[q * 4 + 1];
    float4 dv2 = ((const float4*)d)[q * 4 + 2];
    float4 dv3 = ((const float4*)d)[q * 4 + 3];
    float sc = scale[0];

    int waveId = (blockIdx.x * blockDim.x + threadIdx.x) >> 6;
    int nWaves = (gridDim.x * blockDim.x) >> 6;
    int last = n_edges - 1;

    for (int ebase = waveId * 16; ebase < n_edges; ebase += nWaves * 16) {
        int e0 = ebase + sub;
        int e1 = ebase + 8 + sub;
        bool w0 = (e0 < n_edges);
        bool w1 = (e1 < n_edges);
        int c0 = w0 ? e0 : last;
        int c1 = w1 ? e1 : last;

        int s0 = __builtin_nontemporal_load(src + c0);
        int t0 = __builtin_nontemporal_load(dst + c0);
        int s1 = __builtin_nontemporal_load(src + c1);
        int t1 = __builtin_nontemporal_load(dst + c1);

        const uint4* pa0 = pool + (size_t)s0 * 16 + q * 2;
        const uint4* pb0 = pool + (size_t)t0 * 16 + q * 2;
        const uint4* pa1 = pool + (size_t)s1 * 16 + q * 2;
        const uint4* pb1 = pool + (size_t)t1 * 16 + q * 2;
        uint4 a00 = pa0[0];
        uint4 a01 = pa0[1];
        uint4 b00 = pb0[0];
        uint4 b01 = pb0[1];
        uint4 a10 = pa1[0];
        uint4 a11 = pa1[1];
        uint4 b10 = pb1[0];
        uint4 b11 = pb1[1];

        float p0 = dot8(a00, b00, dv0, dv1, 0.0f);
        p0 = dot8(a01, b01, dv2, dv3, p0);
        float p1 = dot8(a10, b10, dv0, dv1, 0.0f);
        p1 = dot8(a11, b11, dv2, dv3, p1);

        p0 += __shfl_xor(p0, 1);
        p1 += __shfl_xor(p1, 1);
        p0 += __shfl_xor(p0, 2);
        p1 += __shfl_xor(p1, 2);
        p0 += __shfl_xor(p0, 4);
        p1 += __shfl_xor(p1, 4);

        if (q == 0) {
            if (w0) __builtin_nontemporal_store(p0 * sc, out + e0);
            if (w1) __builtin_nontemporal_store(p1 * sc, out + e1);
        }
    }
}

// ---------------- fallback f32 path (proven R1) ----------------

__global__ void inv_norm_kernel(const float* __restrict__ emb,
                                float* __restrict__ inv,
                                int n_nodes) {
    int row = blockIdx.x * (blockDim.x >> 6) + (threadIdx.x >> 6);
    if (row >= n_nodes) return;
    int lane = threadIdx.x & 63;
    const float2* p = (const float2*)(emb + (size_t)row * H);
    float2 v = p[lane];
    float ss = v.x * v.x + v.y * v.y;
#pragma unroll
    for (int off = 32; off; off >>= 1) ss += __shfl_xor(ss, off);
    if (lane == 0) inv[row] = 1.0f / fmaxf(sqrtf(ss), EPS);
}

__global__ void edge_dot_kernel(const float* __restrict__ emb,
                                const float* __restrict__ inv,
                                const int* __restrict__ src,
                                const int* __restrict__ dst,
                                const float* __restrict__ d,
                                const float* __restrict__ scale,
                                float* __restrict__ out,
                                int n_edges) {
    int edge = blockIdx.x * (blockDim.x >> 6) + (threadIdx.x >> 6);
    if (edge >= n_edges) return;
    int lane = threadIdx.x & 63;
    int s = src[edge];
    int t = dst[edge];
    const float2* ps = (const float2*)(emb + (size_t)s * H);
    const float2* pt = (const float2*)(emb + (size_t)t * H);
    float2 dv = ((const float2*)d)[lane];
    float2 a = ps[lane];
    float2 b = pt[lane];
    float p = a.x * dv.x * b.x + a.y * dv.y * b.y;
#pragma unroll
    for (int off = 32; off; off >>= 1) p += __shfl_xor(p, off);
    if (lane == 0) out[edge] = p * inv[s] * inv[t] * scale[0];
}

extern "C" void kernel_launch(void* const* d_in, const int* in_sizes, int n_in,
                              void* d_out, int out_size, void* d_ws, size_t ws_size,
                              hipStream_t stream) {
    const float* emb   = (const float*)d_in[0];
    const int*   src   = (const int*)d_in[1];
    const int*   dst   = (const int*)d_in[2];
    const float* d     = (const float*)d_in[3];
    const float* scale = (const float*)d_in[4];
    float* out = (float*)d_out;

    int n_nodes = in_sizes[0] / H;
    int n_edges = in_sizes[1];
    int nb = (n_nodes + 63) >> 6;  // 64-node buckets

    size_t pool_bytes = (size_t)n_nodes * H * 2;            // 25.6 MB
    size_t sort_bytes = (size_t)n_edges * sizeof(uint4);    // 25.6 MB
    size_t cnt_bytes  = (size_t)nb * sizeof(unsigned int);

    if (ws_size >= pool_bytes + sort_bytes + cnt_bytes) {
        unsigned int* pool   = (unsigned int*)d_ws;
        u32x4*        sorted = (u32x4*)((char*)d_ws + pool_bytes);
        unsigned int* cur    = (unsigned int*)((char*)d_ws + pool_bytes + sort_bytes);

        (void)hipMemsetAsync(cur, 0, cnt_bytes, stream);

        int blocks1 = (n_nodes + 3) / 4;
        norm_quant_kernel<<<blocks1, 256, 0, stream>>>(emb, pool, n_nodes);

        hist_kernel<<<1024, 256, 0, stream>>>(src, cur, n_edges);
        scan_kernel<<<1, 256, 0, stream>>>(cur, nb);
        scatter_kernel<<<2048, 256, 0, stream>>>(src, dst, cur, sorted, n_edges);

        edge_dot_sorted_kernel<<<2048, 256, 0, stream>>>(
            (const uint4*)pool, sorted, d, scale, out, n_edges);
    } else if (ws_size >= pool_bytes) {
        unsigned int* pool = (unsigned int*)d_ws;
        int blocks1 = (n_nodes + 3) / 4;
        norm_quant_kernel<<<blocks1, 256, 0, stream>>>(emb, pool, n_nodes);
        edge_dot_bf16_kernel<<<2048, 256, 0, stream>>>(
            (const uint4*)pool, src, dst, d, scale, out, n_edges);
    } else {
        float* inv = (float*)d_ws;
        int blocks1 = (n_nodes + 3) / 4;
        inv_norm_kernel<<<blocks1, 256, 0, stream>>>(emb, inv, n_nodes);
        int blocks2 = (n_edges + 3) / 4;
        edge_dot_kernel<<<blocks2, 256, 0, stream>>>(emb, inv, src, dst, d,
                                                     scale, out, n_edges);
    }
}

// Round 9
// 199.341 us; speedup vs baseline: 3.0274x; 3.0274x over previous
//
#include <hip/hip_runtime.h>

#define H 128
#define EPS 1e-12f
#define NBLK 256     // partition blocks for hist/scatter (must match)
#define NB_MAX 1600  // max 64-node buckets supported by LDS arrays

typedef unsigned int u32x4 __attribute__((ext_vector_type(4)));

static __device__ __forceinline__ float bf_lo(unsigned int v) {
    return __uint_as_float(v << 16);
}
static __device__ __forceinline__ float bf_hi(unsigned int v) {
    return __uint_as_float(v & 0xFFFF0000u);
}
static __device__ __forceinline__ unsigned int f2bf_rne(float f) {
    unsigned int u = __float_as_uint(f);
    return (u + 0x7FFFu + ((u >> 16) & 1u)) >> 16;
}

// sum over 8 bf16 pairs with diag d folded in
static __device__ __forceinline__ float dot8(uint4 a, uint4 b,
                                             float4 d0, float4 d1, float p) {
    p = fmaf(bf_lo(a.x) * d0.x, bf_lo(b.x), p);
    p = fmaf(bf_hi(a.x) * d0.y, bf_hi(b.x), p);
    p = fmaf(bf_lo(a.y) * d0.z, bf_lo(b.y), p);
    p = fmaf(bf_hi(a.y) * d0.w, bf_hi(b.y), p);
    p = fmaf(bf_lo(a.z) * d1.x, bf_lo(b.z), p);
    p = fmaf(bf_hi(a.z) * d1.y, bf_hi(b.z), p);
    p = fmaf(bf_lo(a.w) * d1.z, bf_lo(b.w), p);
    p = fmaf(bf_hi(a.w) * d1.w, bf_hi(b.w), p);
    return p;
}

// Normalize rows, quantize to bf16, 256B/row pool (row-major).
__global__ void norm_quant_kernel(const float* __restrict__ emb,
                                  unsigned int* __restrict__ pool,
                                  int n_nodes) {
    int row = blockIdx.x * (blockDim.x >> 6) + (threadIdx.x >> 6);
    if (row >= n_nodes) return;
    int lane = threadIdx.x & 63;
    const float* p = emb + (size_t)row * H + lane * 2;
    float vx = __builtin_nontemporal_load(p);
    float vy = __builtin_nontemporal_load(p + 1);
    float ss = vx * vx + vy * vy;
#pragma unroll
    for (int off = 32; off; off >>= 1) ss += __shfl_xor(ss, off);
    float inv = 1.0f / fmaxf(sqrtf(ss), EPS);
    pool[(size_t)row * 64 + lane] =
        f2bf_rne(vx * inv) | (f2bf_rne(vy * inv) << 16);
}

// ---- deterministic bucket sort by src>>6, zero global atomics ----

// Per-block LDS histogram of its contiguous edge chunk -> M[blk][b].
__global__ void hist2_kernel(const int* __restrict__ src,
                             unsigned int* __restrict__ M,  // [NBLK][nb]
                             int n_edges, int nb) {
    __shared__ unsigned int cnt[NB_MAX];
    for (int b = threadIdx.x; b < nb; b += blockDim.x) cnt[b] = 0;
    __syncthreads();
    int ce = (n_edges + NBLK - 1) / NBLK;
    int lo = blockIdx.x * ce;
    int hi = min(lo + ce, n_edges);
    for (int e = lo + (int)threadIdx.x; e < hi; e += blockDim.x) {
        int s = __builtin_nontemporal_load(src + e);
        atomicAdd(&cnt[((unsigned)s) >> 6], 1u);
    }
    __syncthreads();
    unsigned int* row = M + (size_t)blockIdx.x * nb;
    for (int b = threadIdx.x; b < nb; b += blockDim.x) row[b] = cnt[b];
}

// total[b] = sum over blocks of M[blk][b]  (coalesced across threads)
__global__ void colsum_kernel(const unsigned int* __restrict__ M,
                              unsigned int* __restrict__ total, int nb) {
    int b = blockIdx.x * blockDim.x + threadIdx.x;
    if (b >= nb) return;
    unsigned int s = 0;
    for (int j = 0; j < NBLK; ++j) s += M[(size_t)j * nb + b];
    total[b] = s;
}

// single-block in-place exclusive scan (nb <= ~4096)
__global__ void scan_kernel(unsigned int* __restrict__ cur, int nb) {
    __shared__ unsigned int part[256];
    int t = threadIdx.x;
    int chunk = (nb + 255) / 256;
    int lo = t * chunk;
    int hi = lo + chunk < nb ? lo + chunk : nb;
    unsigned int sum = 0;
    for (int i = lo; i < hi; ++i) sum += cur[i];
    part[t] = sum;
    __syncthreads();
    if (t == 0) {
        unsigned int acc = 0;
        for (int i = 0; i < 256; ++i) {
            unsigned int v = part[i];
            part[i] = acc;
            acc += v;
        }
    }
    __syncthreads();
    unsigned int acc = part[t];
    for (int i = lo; i < hi; ++i) {
        unsigned int v = cur[i];
        cur[i] = acc;
        acc += v;
    }
}

// M[blk][b] := base[b] + sum_{k<blk} M[k][b]  (start positions)
__global__ void colprefix_kernel(unsigned int* __restrict__ M,
                                 const unsigned int* __restrict__ base,
                                 int nb) {
    int b = blockIdx.x * blockDim.x + threadIdx.x;
    if (b >= nb) return;
    unsigned int run = base[b];
    for (int j = 0; j < NBLK; ++j) {
        unsigned int t = M[(size_t)j * nb + b];
        M[(size_t)j * nb + b] = run;
        run += t;
    }
}

// Scatter with LDS cursors (intra-block LDS atomics only).
__global__ void scatter2_kernel(const int* __restrict__ src,
                                const int* __restrict__ dst,
                                const unsigned int* __restrict__ M,
                                u32x4* __restrict__ sorted,
                                int n_edges, int nb) {
    __shared__ unsigned int cur[NB_MAX];
    const unsigned int* row = M + (size_t)blockIdx.x * nb;
    for (int b = threadIdx.x; b < nb; b += blockDim.x) cur[b] = row[b];
    __syncthreads();
    int ce = (n_edges + NBLK - 1) / NBLK;
    int lo = blockIdx.x * ce;
    int hi = min(lo + ce, n_edges);
    for (int e = lo + (int)threadIdx.x; e < hi; e += blockDim.x) {
        int s = __builtin_nontemporal_load(src + e);
        int t = __builtin_nontemporal_load(dst + e);
        unsigned int pos = atomicAdd(&cur[((unsigned)s) >> 6], 1u);
        u32x4 rec = {(unsigned)s, (unsigned)t, (unsigned)e, 0u};
        sorted[pos] = rec;
    }
}

// Edge pass over src-sorted edges: 8 lanes/edge, 2 batches per wave-iter.
__global__ void edge_dot_sorted_kernel(const uint4* __restrict__ pool,
                                       const u32x4* __restrict__ sorted,
                                       const float* __restrict__ d,
                                       const float* __restrict__ scale,
                                       float* __restrict__ out,
                                       int n_edges) {
    int lane = threadIdx.x & 63;
    int sub  = lane >> 3;
    int q    = lane & 7;

    float4 dv0 = ((const float4*)d)[q * 4 + 0];
    float4 dv1 = ((const float4*)d)[q * 4 + 1];
    float4 dv2 = ((const float4*)d)[q * 4 + 2];
    float4 dv3 = ((const float4*)d)[q * 4 + 3];
    float sc = scale[0];

    int waveId = (blockIdx.x * blockDim.x + threadIdx.x) >> 6;
    int nWaves = (gridDim.x * blockDim.x) >> 6;
    int last = n_edges - 1;

    for (int ebase = waveId * 16; ebase < n_edges; ebase += nWaves * 16) {
        int e0 = ebase + sub;
        int e1 = ebase + 8 + sub;
        bool w0 = (e0 < n_edges);
        bool w1 = (e1 < n_edges);
        int c0 = w0 ? e0 : last;
        int c1 = w1 ? e1 : last;

        u32x4 r0 = __builtin_nontemporal_load(sorted + c0);
        u32x4 r1 = __builtin_nontemporal_load(sorted + c1);

        const uint4* pa0 = pool + (size_t)r0.x * 16 + q * 2;
        const uint4* pb0 = pool + (size_t)r0.y * 16 + q * 2;
        const uint4* pa1 = pool + (size_t)r1.x * 16 + q * 2;
        const uint4* pb1 = pool + (size_t)r1.y * 16 + q * 2;
        uint4 a00 = pa0[0];
        uint4 a01 = pa0[1];
        uint4 b00 = pb0[0];
        uint4 b01 = pb0[1];
        uint4 a10 = pa1[0];
        uint4 a11 = pa1[1];
        uint4 b10 = pb1[0];
        uint4 b11 = pb1[1];

        float p0 = dot8(a00, b00, dv0, dv1, 0.0f);
        p0 = dot8(a01, b01, dv2, dv3, p0);
        float p1 = dot8(a10, b10, dv0, dv1, 0.0f);
        p1 = dot8(a11, b11, dv2, dv3, p1);

        p0 += __shfl_xor(p0, 1);
        p1 += __shfl_xor(p1, 1);
        p0 += __shfl_xor(p0, 2);
        p1 += __shfl_xor(p1, 2);
        p0 += __shfl_xor(p0, 4);
        p1 += __shfl_xor(p1, 4);

        if (q == 0) {
            if (w0) out[r0.z] = p0 * sc;  // plain: L2 merges scattered 4B
            if (w1) out[r1.z] = p1 * sc;
        }
    }
}

// ---------------- R4 path (proven 124 us total) ----------------

__global__ void edge_dot_bf16_kernel(const uint4* __restrict__ pool,
                                     const int* __restrict__ src,
                                     const int* __restrict__ dst,
                                     const float* __restrict__ d,
                                     const float* __restrict__ scale,
                                     float* __restrict__ out,
                                     int n_edges) {
    int lane = threadIdx.x & 63;
    int sub  = lane >> 3;
    int q    = lane & 7;

    float4 dv0 = ((const float4*)d)[q * 4 + 0];
    float4 dv1 = ((const float4*)d)[q * 4 + 1];
    float4 dv2 = ((const float4*)d)[q * 4 + 2];
    float4 dv3 = ((const float4*)d)[q * 4 + 3];
    float sc = scale[0];

    int waveId = (blockIdx.x * blockDim.x + threadIdx.x) >> 6;
    int nWaves = (gridDim.x * blockDim.x) >> 6;
    int last = n_edges - 1;

    for (int ebase = waveId * 16; ebase < n_edges; ebase += nWaves * 16) {
        int e0 = ebase + sub;
        int e1 = ebase + 8 + sub;
        bool w0 = (e0 < n_edges);
        bool w1 = (e1 < n_edges);
        int c0 = w0 ? e0 : last;
        int c1 = w1 ? e1 : last;

        int s0 = __builtin_nontemporal_load(src + c0);
        int t0 = __builtin_nontemporal_load(dst + c0);
        int s1 = __builtin_nontemporal_load(src + c1);
        int t1 = __builtin_nontemporal_load(dst + c1);

        const uint4* pa0 = pool + (size_t)s0 * 16 + q * 2;
        const uint4* pb0 = pool + (size_t)t0 * 16 + q * 2;
        const uint4* pa1 = pool + (size_t)s1 * 16 + q * 2;
        const uint4* pb1 = pool + (size_t)t1 * 16 + q * 2;
        uint4 a00 = pa0[0];
        uint4 a01 = pa0[1];
        uint4 b00 = pb0[0];
        uint4 b01 = pb0[1];
        uint4 a10 = pa1[0];
        uint4 a11 = pa1[1];
        uint4 b10 = pb1[0];
        uint4 b11 = pb1[1];

        float p0 = dot8(a00, b00, dv0, dv1, 0.0f);
        p0 = dot8(a01, b01, dv2, dv3, p0);
        float p1 = dot8(a10, b10, dv0, dv1, 0.0f);
        p1 = dot8(a11, b11, dv2, dv3, p1);

        p0 += __shfl_xor(p0, 1);
        p1 += __shfl_xor(p1, 1);
        p0 += __shfl_xor(p0, 2);
        p1 += __shfl_xor(p1, 2);
        p0 += __shfl_xor(p0, 4);
        p1 += __shfl_xor(p1, 4);

        if (q == 0) {
            if (w0) __builtin_nontemporal_store(p0 * sc, out + e0);
            if (w1) __builtin_nontemporal_store(p1 * sc, out + e1);
        }
    }
}

// ---------------- fallback f32 path (proven R1) ----------------

__global__ void inv_norm_kernel(const float* __restrict__ emb,
                                float* __restrict__ inv,
                                int n_nodes) {
    int row = blockIdx.x * (blockDim.x >> 6) + (threadIdx.x >> 6);
    if (row >= n_nodes) return;
    int lane = threadIdx.x & 63;
    const float2* p = (const float2*)(emb + (size_t)row * H);
    float2 v = p[lane];
    float ss = v.x * v.x + v.y * v.y;
#pragma unroll
    for (int off = 32; off; off >>= 1) ss += __shfl_xor(ss, off);
    if (lane == 0) inv[row] = 1.0f / fmaxf(sqrtf(ss), EPS);
}

__global__ void edge_dot_kernel(const float* __restrict__ emb,
                                const float* __restrict__ inv,
                                const int* __restrict__ src,
                                const int* __restrict__ dst,
                                const float* __restrict__ d,
                                const float* __restrict__ scale,
                                float* __restrict__ out,
                                int n_edges) {
    int edge = blockIdx.x * (blockDim.x >> 6) + (threadIdx.x >> 6);
    if (edge >= n_edges) return;
    int lane = threadIdx.x & 63;
    int s = src[edge];
    int t = dst[edge];
    const float2* ps = (const float2*)(emb + (size_t)s * H);
    const float2* pt = (const float2*)(emb + (size_t)t * H);
    float2 dv = ((const float2*)d)[lane];
    float2 a = ps[lane];
    float2 b = pt[lane];
    float p = a.x * dv.x * b.x + a.y * dv.y * b.y;
#pragma unroll
    for (int off = 32; off; off >>= 1) p += __shfl_xor(p, off);
    if (lane == 0) out[edge] = p * inv[s] * inv[t] * scale[0];
}

extern "C" void kernel_launch(void* const* d_in, const int* in_sizes, int n_in,
                              void* d_out, int out_size, void* d_ws, size_t ws_size,
                              hipStream_t stream) {
    const float* emb   = (const float*)d_in[0];
    const int*   src   = (const int*)d_in[1];
    const int*   dst   = (const int*)d_in[2];
    const float* d     = (const float*)d_in[3];
    const float* scale = (const float*)d_in[4];
    float* out = (float*)d_out;

    int n_nodes = in_sizes[0] / H;
    int n_edges = in_sizes[1];
    int nb = (n_nodes + 63) >> 6;  // 64-node buckets

    size_t pool_bytes = (size_t)n_nodes * H * 2;               // 25.6 MB
    size_t sort_bytes = (size_t)n_edges * 16;                  // 25.6 MB
    size_t M_bytes    = (size_t)NBLK * nb * sizeof(unsigned);  // 1.6 MB
    size_t tot_bytes  = (size_t)nb * sizeof(unsigned);

    if (nb <= NB_MAX &&
        ws_size >= pool_bytes + sort_bytes + M_bytes + tot_bytes) {
        unsigned int* pool   = (unsigned int*)d_ws;
        u32x4*        sorted = (u32x4*)((char*)d_ws + pool_bytes);
        unsigned int* M      = (unsigned int*)((char*)d_ws + pool_bytes + sort_bytes);
        unsigned int* base   = (unsigned int*)((char*)d_ws + pool_bytes + sort_bytes + M_bytes);

        int blocks1 = (n_nodes + 3) / 4;
        norm_quant_kernel<<<blocks1, 256, 0, stream>>>(emb, pool, n_nodes);

        int nbg = (nb + 255) / 256;
        hist2_kernel<<<NBLK, 256, 0, stream>>>(src, M, n_edges, nb);
        colsum_kernel<<<nbg, 256, 0, stream>>>(M, base, nb);
        scan_kernel<<<1, 256, 0, stream>>>(base, nb);
        colprefix_kernel<<<nbg, 256, 0, stream>>>(M, base, nb);
        scatter2_kernel<<<NBLK, 256, 0, stream>>>(src, dst, M, sorted,
                                                  n_edges, nb);

        edge_dot_sorted_kernel<<<2048, 256, 0, stream>>>(
            (const uint4*)pool, sorted, d, scale, out, n_edges);
    } else if (ws_size >= pool_bytes) {
        unsigned int* pool = (unsigned int*)d_ws;
        int blocks1 = (n_nodes + 3) / 4;
        norm_quant_kernel<<<blocks1, 256, 0, stream>>>(emb, pool, n_nodes);
        edge_dot_bf16_kernel<<<2048, 256, 0, stream>>>(
            (const uint4*)pool, src, dst, d, scale, out, n_edges);
    } else {
        float* inv = (float*)d_ws;
        int blocks1 = (n_nodes + 3) / 4;
        inv_norm_kernel<<<blocks1, 256, 0, stream>>>(emb, inv, n_nodes);
        int blocks2 = (n_edges + 3) / 4;
        edge_dot_kernel<<<blocks2, 256, 0, stream>>>(emb, inv, src, dst, d,
                                                     scale, out, n_edges);
    }
}